// Round 6
// baseline (165.637 us; speedup 1.0000x reference)
//
#include <hip/hip_runtime.h>
#include <stdint.h>

// Ragged masked softmax + JAX-exact threefry dropout (partitionable path).
// One 64-lane wave per row. No max-subtraction (shift-invariant, inputs bounded).
// Single-pass compute with register-pinned intermediates:
//   pass 1: load -> exp -> threefry -> w = (keep ? e : 0), PIN w in a VGPR
//           (asm "+v" makes w opaque: recompute downstream is illegal)
//   pass 2: out = w * inv   (2 instr/elem)
// Round-4/5 lesson: LDS staging and plain register arrays both got
// rematerialized by the compiler (LDS_Block_Size=0, double threefry).
//
// bits[i] = o0 ^ o1, (o0,o1) = threefry2x32(key=(0,42), msg=(0, i))
// keep    = bits < 0xE6666600u   (exact integer form of uniform(bits) < 0.9f)

__device__ __forceinline__ uint32_t rotl32(uint32_t v, int r) {
  return __builtin_amdgcn_alignbit(v, v, 32 - r);  // rotr(v,32-r) == rotl(v,r)
}

// key = (0, 42): ks0 = 0, ks1 = 42, ks2 = 0x1BD11BDA ^ 0 ^ 42 = 0x1BD11BF0
__device__ __forceinline__ uint32_t tf_bits(uint32_t i) {
  uint32_t x0 = 0u;        // msg hi word (+ ks0 = 0)
  uint32_t x1 = i + 42u;   // msg lo word + ks1
#define TF_ROUND(r) { x0 += x1; x1 = rotl32(x1, (r)); x1 ^= x0; }
  TF_ROUND(13) TF_ROUND(15) TF_ROUND(26) TF_ROUND(6)
  x0 += 42u;          x1 += 0x1BD11BF1u;   // (ks1, ks2+1)
  TF_ROUND(17) TF_ROUND(29) TF_ROUND(16) TF_ROUND(24)
  x0 += 0x1BD11BF0u;  x1 += 2u;            // (ks2, ks0+2)
  TF_ROUND(13) TF_ROUND(15) TF_ROUND(26) TF_ROUND(6)
  /* x0 += ks0 (=0) */ x1 += 45u;          // (ks0, ks1+3)
  TF_ROUND(17) TF_ROUND(29) TF_ROUND(16) TF_ROUND(24)
  x0 += 42u;          x1 += 0x1BD11BF4u;   // (ks1, ks2+4)
  TF_ROUND(13) TF_ROUND(15) TF_ROUND(26) TF_ROUND(6)
  x0 += 0x1BD11BF0u;  x1 += 5u;            // (ks2, ks0+5)
#undef TF_ROUND
  return x0 ^ x1;
}

template <int S>
__device__ __forceinline__ void do_row(const float* __restrict__ in,
                                       const float* __restrict__ mask,
                                       float* __restrict__ out,
                                       uint32_t rowbase, int mask_base, int lane) {
  constexpr int NC = S / 128;  // chunks of 128 elems (64 lanes x float2)
  const float* pin = in + rowbase + (lane << 1);
  const float* pmk = mask + mask_base + (lane << 1);
  float* pot       = out + rowbase + (lane << 1);
  const uint32_t gl = rowbase + (uint32_t)(lane << 1);

  float w[2 * NC];
  float s = 0.0f;
#pragma unroll
  for (int c = 0; c < NC; ++c) {
    const float2 v  = *reinterpret_cast<const float2*>(pin + (c << 7));
    const float2 mk = *reinterpret_cast<const float2*>(pmk + (c << 7));
    const float e0 = __expf(v.x + mk.x);
    const float e1 = __expf(v.y + mk.y);
    s += e0 + e1;                      // sum over ALL e (dropout skips denom)
    const uint32_t g0 = gl + (uint32_t)(c << 7);
    const uint32_t b0 = tf_bits(g0);
    const uint32_t b1 = tf_bits(g0 + 1u);
    w[2 * c]     = (b0 < 0xE6666600u) ? e0 : 0.0f;
    w[2 * c + 1] = (b1 < 0xE6666600u) ? e1 : 0.0f;
    // Pin: value becomes an opaque asm output -> compiler cannot
    // rematerialize exp/threefry in the store pass.
    asm volatile("" : "+v"(w[2 * c]));
    asm volatile("" : "+v"(w[2 * c + 1]));
  }
#pragma unroll
  for (int o = 32; o >= 1; o >>= 1) s += __shfl_xor(s, o);
  const float inv = 1.0f / (s * 0.9f);  // softmax denom fused with 1/(1-p)

#pragma unroll
  for (int c = 0; c < NC; ++c) {
    *reinterpret_cast<float2*>(pot + (c << 7)) =
        make_float2(w[2 * c] * inv, w[2 * c + 1] * inv);
  }
}

__global__ __launch_bounds__(256) void BaseMaskSoftmaxDropout_kernel(
    const float* __restrict__ in, const float* __restrict__ mask,
    float* __restrict__ out) {
  const int wid  = ((blockIdx.x << 8) + (int)threadIdx.x) >> 6;
  const int lane = (int)threadIdx.x & 63;

  // Hardcoded per-batch tables (SEQLENS = {1024,768,512,896,640,384,1024,512}, HEADS=16)
  constexpr int nb = 8;
  constexpr int seq[nb]         = {1024, 768, 512, 896, 640, 384, 1024, 512};
  constexpr int rowst[nb + 1]   = {0, 16384, 28672, 36864, 51200, 61440, 67584, 83968, 92160};
  constexpr uint32_t elemst[nb] = {0u, 16777216u, 26214400u, 30408704u,
                                   43253760u, 49807360u, 52166656u, 68943872u};
  constexpr int maskst[nb]      = {0, 1024, 1792, 2304, 3200, 3840, 4224, 5248};

  int b = 0;
#pragma unroll
  for (int i = 1; i < nb; ++i)
    if (wid >= rowst[i]) b = i;

  const int rb = wid - rowst[b];
  const int Sv = seq[b];
  const uint32_t rowbase = elemst[b] + (uint32_t)rb * (uint32_t)Sv;
  const int mb = maskst[b];

  switch (Sv) {
    case 1024: do_row<1024>(in, mask, out, rowbase, mb, lane); break;
    case 896:  do_row<896>(in, mask, out, rowbase, mb, lane); break;
    case 768:  do_row<768>(in, mask, out, rowbase, mb, lane); break;
    case 640:  do_row<640>(in, mask, out, rowbase, mb, lane); break;
    case 512:  do_row<512>(in, mask, out, rowbase, mb, lane); break;
    case 384:  do_row<384>(in, mask, out, rowbase, mb, lane); break;
  }
}

extern "C" void kernel_launch(void* const* d_in, const int* in_sizes, int n_in,
                              void* d_out, int out_size, void* d_ws, size_t ws_size,
                              hipStream_t stream) {
  const float* in   = (const float*)d_in[0];
  const float* mask = (const float*)d_in[1];
  float* out        = (float*)d_out;

  // R_TOTAL = 92160 rows, 4 waves (rows) per 256-thread block
  const int blocks = 92160 / 4;
  hipLaunchKernelGGL(BaseMaskSoftmaxDropout_kernel, dim3(blocks), dim3(256), 0,
                     stream, in, mask, out);
}

// Round 7
// 165.615 us; speedup vs baseline: 1.0001x; 1.0001x over previous
//
#include <hip/hip_runtime.h>
#include <stdint.h>

// Ragged masked softmax + JAX-exact threefry dropout (partitionable path).
// One 64-lane wave per row. No max-subtraction (shift-invariant, inputs bounded).
// TRUE single-pass: w = (keep ? e : 0) pinned in VGPRs with an asm that also
// "writes" s — the wave reduce reading s cannot start until w exists, and the
// opaque asm output cannot be rematerialized, so the compiler can neither sink
// the pins below the reduce (rounds 5/6 failure) nor re-run loads/exp/threefry.
//
// bits[i] = o0 ^ o1, (o0,o1) = threefry2x32(key=(0,42), msg=(0, i))
// keep    = bits < 0xE6666600u   (exact integer form of uniform(bits) < 0.9f)

__device__ __forceinline__ uint32_t rotl32(uint32_t v, int r) {
  return __builtin_amdgcn_alignbit(v, v, 32 - r);  // rotr(v,32-r) == rotl(v,r)
}

// key = (0, 42): ks0 = 0, ks1 = 42, ks2 = 0x1BD11BDA ^ 0 ^ 42 = 0x1BD11BF0
__device__ __forceinline__ uint32_t tf_bits(uint32_t i) {
  uint32_t x0 = 0u;        // msg hi word (+ ks0 = 0)
  uint32_t x1 = i + 42u;   // msg lo word + ks1
#define TF_ROUND(r) { x0 += x1; x1 = rotl32(x1, (r)); x1 ^= x0; }
  TF_ROUND(13) TF_ROUND(15) TF_ROUND(26) TF_ROUND(6)
  x0 += 42u;          x1 += 0x1BD11BF1u;   // (ks1, ks2+1)
  TF_ROUND(17) TF_ROUND(29) TF_ROUND(16) TF_ROUND(24)
  x0 += 0x1BD11BF0u;  x1 += 2u;            // (ks2, ks0+2)
  TF_ROUND(13) TF_ROUND(15) TF_ROUND(26) TF_ROUND(6)
  /* x0 += ks0 (=0) */ x1 += 45u;          // (ks0, ks1+3)
  TF_ROUND(17) TF_ROUND(29) TF_ROUND(16) TF_ROUND(24)
  x0 += 42u;          x1 += 0x1BD11BF4u;   // (ks1, ks2+4)
  TF_ROUND(13) TF_ROUND(15) TF_ROUND(26) TF_ROUND(6)
  x0 += 0x1BD11BF0u;  x1 += 5u;            // (ks2, ks0+5)
#undef TF_ROUND
  return x0 ^ x1;
}

template <int S>
__device__ __forceinline__ void do_row(const float* __restrict__ in,
                                       const float* __restrict__ mask,
                                       float* __restrict__ out,
                                       uint32_t rowbase, int mask_base, int lane) {
  constexpr int NC = S / 128;  // chunks of 128 elems (64 lanes x float2)
  const float* pin = in + rowbase + (lane << 1);
  const float* pmk = mask + mask_base + (lane << 1);
  float* pot       = out + rowbase + (lane << 1);
  const uint32_t gl = rowbase + (uint32_t)(lane << 1);

  float w0[NC], w1[NC];
  float s = 0.0f;
#pragma unroll
  for (int c = 0; c < NC; ++c) {
    const float2 v  = *reinterpret_cast<const float2*>(pin + (c << 7));
    const float2 mk = *reinterpret_cast<const float2*>(pmk + (c << 7));
    const float e0 = __expf(v.x + mk.x);
    const float e1 = __expf(v.y + mk.y);
    s += e0 + e1;                      // sum over ALL e (dropout skips denom)
    const uint32_t g0 = gl + (uint32_t)(c << 7);
    const uint32_t b0 = tf_bits(g0);
    const uint32_t b1 = tf_bits(g0 + 1u);
    w0[c] = (b0 < 0xE6666600u) ? e0 : 0.0f;
    w1[c] = (b1 < 0xE6666600u) ? e1 : 0.0f;
    // Pin w AND chain through s: reduce can't start before w exists; w can't
    // be rematerialized after. Forces genuine single-pass codegen.
    asm volatile("" : "+v"(w0[c]), "+v"(w1[c]), "+v"(s));
  }
#pragma unroll
  for (int o = 32; o >= 1; o >>= 1) s += __shfl_xor(s, o);
  const float inv = 1.0f / (s * 0.9f);  // softmax denom fused with 1/(1-p)

#pragma unroll
  for (int c = 0; c < NC; ++c) {
    *reinterpret_cast<float2*>(pot + (c << 7)) =
        make_float2(w0[c] * inv, w1[c] * inv);
  }
}

__global__ __launch_bounds__(256) void BaseMaskSoftmaxDropout_kernel(
    const float* __restrict__ in, const float* __restrict__ mask,
    float* __restrict__ out) {
  const int wid  = ((blockIdx.x << 8) + (int)threadIdx.x) >> 6;
  const int lane = (int)threadIdx.x & 63;

  // Hardcoded per-batch tables (SEQLENS = {1024,768,512,896,640,384,1024,512}, HEADS=16)
  constexpr int nb = 8;
  constexpr int seq[nb]         = {1024, 768, 512, 896, 640, 384, 1024, 512};
  constexpr int rowst[nb + 1]   = {0, 16384, 28672, 36864, 51200, 61440, 67584, 83968, 92160};
  constexpr uint32_t elemst[nb] = {0u, 16777216u, 26214400u, 30408704u,
                                   43253760u, 49807360u, 52166656u, 68943872u};
  constexpr int maskst[nb]      = {0, 1024, 1792, 2304, 3200, 3840, 4224, 5248};

  int b = 0;
#pragma unroll
  for (int i = 1; i < nb; ++i)
    if (wid >= rowst[i]) b = i;

  const int rb = wid - rowst[b];
  const int Sv = seq[b];
  const uint32_t rowbase = elemst[b] + (uint32_t)rb * (uint32_t)Sv;
  const int mb = maskst[b];

  switch (Sv) {
    case 1024: do_row<1024>(in, mask, out, rowbase, mb, lane); break;
    case 896:  do_row<896>(in, mask, out, rowbase, mb, lane); break;
    case 768:  do_row<768>(in, mask, out, rowbase, mb, lane); break;
    case 640:  do_row<640>(in, mask, out, rowbase, mb, lane); break;
    case 512:  do_row<512>(in, mask, out, rowbase, mb, lane); break;
    case 384:  do_row<384>(in, mask, out, rowbase, mb, lane); break;
  }
}

extern "C" void kernel_launch(void* const* d_in, const int* in_sizes, int n_in,
                              void* d_out, int out_size, void* d_ws, size_t ws_size,
                              hipStream_t stream) {
  const float* in   = (const float*)d_in[0];
  const float* mask = (const float*)d_in[1];
  float* out        = (float*)d_out;

  // R_TOTAL = 92160 rows, 4 waves (rows) per 256-thread block
  const int blocks = 92160 / 4;
  hipLaunchKernelGGL(BaseMaskSoftmaxDropout_kernel, dim3(blocks), dim3(256), 0,
                     stream, in, mask, out);
}